// Round 10
// baseline (248.595 us; speedup 1.0000x reference)
//
#include <hip/hip_runtime.h>
#include <math.h>

#define NN 50000
#define NE 800000
#define NBK 782   // ceil(NN/64) 64-node dst buckets
#define CSTR 16   // counter stride (ints) -> one counter per 64B line

typedef __bf16 bf16x8 __attribute__((ext_vector_type(8)));
typedef float  f32x4  __attribute__((ext_vector_type(4)));

__device__ __forceinline__ ushort f2b(float f) {
  union { float f; uint u; } v; v.f = f;
  uint u = v.u;
  return (ushort)((u + 0x7fffu + ((u >> 16) & 1u)) >> 16);  // RNE
}
__device__ __forceinline__ float b2f(ushort b) {
  union { uint u; float f; } v; v.u = ((uint)b) << 16;
  return v.f;
}
__device__ __forceinline__ uint4 cvt8(const float* p) {
  float4 a = *(const float4*)p, b = *(const float4*)(p + 4);
  uint4 u;
  u.x = (uint)f2b(a.x) | ((uint)f2b(a.y) << 16);
  u.y = (uint)f2b(a.z) | ((uint)f2b(a.w) << 16);
  u.z = (uint)f2b(b.x) | ((uint)f2b(b.y) << 16);
  u.w = (uint)f2b(b.z) | ((uint)f2b(b.w) << 16);
  return u;
}

// ---------------------------------------------------------------------------
// cvt_w: weights -> bf16, transposed to [n][k]
// ---------------------------------------------------------------------------
__global__ __launch_bounds__(256) void cvt_w(const float* __restrict__ Wfc,
    const float* __restrict__ Wpr, const float* __restrict__ Wgt,
    ushort* __restrict__ Tfc, ushort* __restrict__ Tpr, ushort* __restrict__ Tgt) {
  int t = blockIdx.x * 256 + threadIdx.x;
  if (t < 16384) {
    int n = t >> 7, k = t & 127;
    Tfc[n * 128 + k] = f2b(Wfc[k * 128 + n]);
  } else if (t < 32768) {
    int i = t - 16384; int n = i >> 7, k = i & 127;
    Tpr[n * 128 + k] = f2b(Wpr[k * 128 + n]);
  } else if (t < 65536) {
    int i = t - 32768; int n = i >> 8, k = i & 255;
    Tgt[n * 256 + k] = f2b(Wgt[k * 128 + n]);
  }
}

// ---------------------------------------------------------------------------
// bucket histogram: LDS-binned, one padded global atomic per bucket per block.
// ---------------------------------------------------------------------------
__global__ __launch_bounds__(1024) void bhist(const int* __restrict__ dst,
                                              int* __restrict__ gcnt) {
  __shared__ int lcnt[NBK];
  const int tid = threadIdx.x;
  for (int i = tid; i < NBK; i += 1024) lcnt[i] = 0;
  __syncthreads();
  for (int e = blockIdx.x * 1024 + tid; e < NE; e += 64 * 1024)
    atomicAdd(&lcnt[dst[e] >> 6], 1);
  __syncthreads();
  for (int i = tid; i < NBK; i += 1024) {
    int c = lcnt[i];
    if (c) atomicAdd(&gcnt[i * CSTR], c);
  }
}

// single-block exclusive scan over NBK bucket counts -> boff + gcursor(padded)
__global__ __launch_bounds__(256) void bscan(const int* __restrict__ gcnt,
                                             int* __restrict__ boff,
                                             int* __restrict__ gcursor) {
  __shared__ int ws[4];
  __shared__ int carry;
  const int tid = threadIdx.x, ln = tid & 63, wv = tid >> 6;
  if (tid == 0) carry = 0;
  __syncthreads();
  for (int base = 0; base < NBK; base += 256) {
    int i = base + tid;
    int x = (i < NBK) ? gcnt[i * CSTR] : 0;
    int v = x;
#pragma unroll
    for (int d = 1; d < 64; d <<= 1) {
      int t = __shfl_up(v, d);
      if (ln >= d) v += t;
    }
    if (ln == 63) ws[wv] = v;
    __syncthreads();
    int w0 = ws[0], w1 = ws[1], w2 = ws[2], w3 = ws[3];
    int woff = (wv == 0) ? 0 : (wv == 1) ? w0 : (wv == 2) ? w0 + w1 : w0 + w1 + w2;
    int excl = carry + woff + v - x;
    if (i < NBK) { boff[i] = excl; gcursor[i * CSTR] = excl; }
    int tot = w0 + w1 + w2 + w3;
    __syncthreads();
    if (tid == 0) carry += tot;
    __syncthreads();
  }
  if (threadIdx.x == 0) boff[NBK] = NE;
}

// ---------------------------------------------------------------------------
// bucket scatter: 64 blocks x 1024 thr (runs ~16 edges = 64B per bucket).
// packed (src<<6 | dstLow) appended via padded gcursor reserve.
// ---------------------------------------------------------------------------
__global__ __launch_bounds__(1024) void bscatter(const int* __restrict__ src,
    const int* __restrict__ dst, int* __restrict__ gcursor,
    uint* __restrict__ packed) {
  __shared__ int lcnt[NBK];
  __shared__ int lbase[NBK];
  __shared__ int lrank[NBK];
  const int tid = threadIdx.x;
  const int PER = (NE + 63) / 64;   // 12500
  const int e0 = blockIdx.x * PER;
  const int e1 = min(NE, e0 + PER);
  for (int i = tid; i < NBK; i += 1024) { lcnt[i] = 0; lrank[i] = 0; }
  __syncthreads();
  for (int e = e0 + tid; e < e1; e += 1024) atomicAdd(&lcnt[dst[e] >> 6], 1);
  __syncthreads();
  for (int i = tid; i < NBK; i += 1024) {
    int c = lcnt[i];
    lbase[i] = c ? atomicAdd(&gcursor[i * CSTR], c) : 0;
  }
  __syncthreads();
  for (int e = e0 + tid; e < e1; e += 1024) {
    int d = dst[e], b = d >> 6;
    int r = atomicAdd(&lrank[b], 1);
    packed[lbase[b] + r] = ((uint)src[e] << 6) | (uint)(d & 63);
  }
}

// ---------------------------------------------------------------------------
// per-bucket counting sort + FUSED attention coefficients:
// packed -> node-sorted ssrc + CSR (row_off, deg) + a_srt[slot] = 4 bf16
// a = exp(leakyrelu(el[src][h] + er[node][h])). er staged in LDS.
// ---------------------------------------------------------------------------
__global__ __launch_bounds__(256) void bsort(const uint* __restrict__ packed,
    const int* __restrict__ boff, const float* __restrict__ el,
    const float* __restrict__ er, int* __restrict__ ssrc,
    uint2* __restrict__ a_srt, int* __restrict__ row_off,
    int* __restrict__ deg) {
  __shared__ int cnt[64], base[64], rank[64];
  __shared__ float ers[64 * 4];
  const int b = blockIdx.x, tid = threadIdx.x;
  const int e0 = boff[b], e1 = boff[b + 1];
  if (tid < 64) { cnt[tid] = 0; rank[tid] = 0; }
  {
    int node = b * 64 + (tid >> 2);
    ers[tid] = (node < NN) ? er[node * 4 + (tid & 3)] : 0.f;
  }
  __syncthreads();
  for (int e = e0 + tid; e < e1; e += 256)
    atomicAdd(&cnt[packed[e] & 63], 1);
  __syncthreads();
  if (tid < 64) {                      // wave 0: scan 64 counts
    int x = cnt[tid];
    int v = x;
#pragma unroll
    for (int d = 1; d < 64; d <<= 1) {
      int t = __shfl_up(v, d);
      if (tid >= d) v += t;
    }
    base[tid] = v - x;
    int node = b * 64 + tid;
    if (node < NN) { row_off[node] = e0 + v - x; deg[node] = x; }
  }
  __syncthreads();
  for (int e = e0 + tid; e < e1; e += 256) {
    uint p = packed[e];
    int dl = p & 63;
    int s  = (int)(p >> 6);
    int r = atomicAdd(&rank[dl], 1);
    int slot = e0 + base[dl] + r;
    ssrc[slot] = s;
    float4 ev = *(const float4*)(el + (size_t)s * 4);
    float v0 = ev.x + ers[dl * 4 + 0];
    float v1 = ev.y + ers[dl * 4 + 1];
    float v2 = ev.z + ers[dl * 4 + 2];
    float v3 = ev.w + ers[dl * 4 + 3];
    v0 = v0 > 0.f ? v0 : 0.2f * v0;
    v1 = v1 > 0.f ? v1 : 0.2f * v1;
    v2 = v2 > 0.f ? v2 : 0.2f * v2;
    v3 = v3 > 0.f ? v3 : 0.2f * v3;
    float a0 = __expf(v0), a1 = __expf(v1);
    float a2 = __expf(v2), a3 = __expf(v3);
    uint2 aw;
    aw.x = (uint)f2b(a0) | ((uint)f2b(a1) << 16);
    aw.y = (uint)f2b(a2) | ((uint)f2b(a3) << 16);
    a_srt[slot] = aw;
  }
}

// ---------------------------------------------------------------------------
// MFMA GEMM: feat = h(f32,staged-cvt) @ Wfc^T, fused el/er epilogue.
// 64-row tiles, 4 waves (2x2), wave = 32x64 (acc[2][4]).
// A-tile in LDS (XOR-swizzled); B fragments direct from global.
// ---------------------------------------------------------------------------
__global__ __launch_bounds__(256) void mgemm0(
    const float* __restrict__ A0f, const ushort* __restrict__ Wt,
    const float* __restrict__ al, const float* __restrict__ ar,
    float* __restrict__ el, float* __restrict__ er,
    ushort* __restrict__ outb, int M)
{
  __shared__ char As[64 * 256];
  const int tid  = threadIdx.x;
  const int row0 = blockIdx.x * 64;

#pragma unroll
  for (int c = 0; c < 4; c++) {
    int idx = tid + c * 256;
    int r  = idx >> 4;
    int kc = idx & 15;
    int sw = ((kc * 16) ^ ((r & 7) << 4));
    uint4 va = make_uint4(0u, 0u, 0u, 0u);
    if (row0 + r < M) va = cvt8(A0f + (size_t)(row0 + r) * 128 + kc * 8);
    *(uint4*)(As + r * 256 + sw) = va;
  }
  __syncthreads();

  const int ln = tid & 63, wv = tid >> 6;
  const int wm = wv >> 1, wn = wv & 1;
  const int lr = ln & 15, lk = ln >> 4;

  f32x4 acc[2][4] = {};
#pragma unroll
  for (int ks = 0; ks < 4; ks++) {
    int k2 = ks * 64 + lk * 16;
    bf16x8 af[2], bfr[4];
#pragma unroll
    for (int mt = 0; mt < 2; mt++) {
      int arr = wm * 32 + mt * 16 + lr;
      af[mt] = *(const bf16x8*)(As + arr * 256 + (k2 ^ ((arr & 7) << 4)));
    }
#pragma unroll
    for (int nt = 0; nt < 4; nt++) {
      int bn = wn * 64 + nt * 16 + lr;
      bfr[nt] = *(const bf16x8*)(Wt + (size_t)bn * 128 + ks * 32 + lk * 8);
    }
#pragma unroll
    for (int mt = 0; mt < 2; mt++)
#pragma unroll
      for (int nt = 0; nt < 4; nt++)
        acc[mt][nt] = __builtin_amdgcn_mfma_f32_16x16x32_bf16(
            af[mt], bfr[nt], acc[mt][nt], 0, 0, 0);
  }

  float alv[4], arv[4];
#pragma unroll
  for (int nt = 0; nt < 4; nt++) {
    int col = wn * 64 + nt * 16 + lr;
    alv[nt] = al[col]; arv[nt] = ar[col];
  }
#pragma unroll
  for (int mt = 0; mt < 2; mt++) {
#pragma unroll
    for (int r = 0; r < 4; r++) {
      int row = row0 + wm * 32 + mt * 16 + lk * 4 + r;
      float pl0 = acc[mt][0][r] * alv[0] + acc[mt][1][r] * alv[1];
      float pl1 = acc[mt][2][r] * alv[2] + acc[mt][3][r] * alv[3];
      float pr0 = acc[mt][0][r] * arv[0] + acc[mt][1][r] * arv[1];
      float pr1 = acc[mt][2][r] * arv[2] + acc[mt][3][r] * arv[3];
#pragma unroll
      for (int m2 = 1; m2 < 16; m2 <<= 1) {
        pl0 += __shfl_xor(pl0, m2); pl1 += __shfl_xor(pl1, m2);
        pr0 += __shfl_xor(pr0, m2); pr1 += __shfl_xor(pr1, m2);
      }
      if (row < M) {
#pragma unroll
        for (int nt = 0; nt < 4; nt++)
          outb[(size_t)row * 128 + wn * 64 + nt * 16 + lr] = f2b(acc[mt][nt][r]);
        if (lr == 0) {
          *(float2*)(el + row * 4 + 2 * wn) = make_float2(pl0, pl1);
          *(float2*)(er + row * 4 + 2 * wn) = make_float2(pr0, pr1);
        }
      }
    }
  }
}

// ---------------------------------------------------------------------------
// Fused projection + gate kernel (unchanged from R8).
// ---------------------------------------------------------------------------
__global__ __launch_bounds__(256) void pg_k(
    const ushort* __restrict__ hgatb, const float* __restrict__ ctx,
    const ushort* __restrict__ Tpr, const ushort* __restrict__ Tgt,
    const float* __restrict__ b_proj, const float* __restrict__ b_gate,
    float* __restrict__ out, int M)
{
  __shared__ char As[64 * 256];   // hgat tile (16KB)
  __shared__ char Hs[64 * 512];   // [hp | ctx] bf16 (32KB)
  const int tid  = threadIdx.x;
  const int row0 = blockIdx.x * 64;

#pragma unroll
  for (int c = 0; c < 4; c++) {
    int idx = tid + c * 256;
    int r = idx >> 4, kc = idx & 15;
    int sw = (kc * 16) ^ ((r & 7) << 4);
    uint4 va = make_uint4(0u, 0u, 0u, 0u);
    if (row0 + r < M) va = *(const uint4*)(hgatb + (size_t)(row0 + r) * 128 + kc * 8);
    *(uint4*)(As + r * 256 + sw) = va;
  }
#pragma unroll
  for (int c = 0; c < 4; c++) {
    int idx = tid + c * 256;
    int r = idx >> 4, kc = (idx & 15) + 16;
    int sw = (kc * 16) ^ ((r & 7) << 4);
    uint4 va = make_uint4(0u, 0u, 0u, 0u);
    if (row0 + r < M) va = cvt8(ctx + (size_t)(row0 + r) * 128 + (kc - 16) * 8);
    *(uint4*)(Hs + r * 512 + sw) = va;
  }
  __syncthreads();

  const int ln = tid & 63, wv = tid >> 6;
  const int wm = wv >> 1, wn = wv & 1;
  const int lr = ln & 15, lk = ln >> 4;

  float bpv[4], bgv[4];
#pragma unroll
  for (int nt = 0; nt < 4; nt++) {
    int col = wn * 64 + nt * 16 + lr;
    bpv[nt] = b_proj[col]; bgv[nt] = b_gate[col];
  }

  // MFMA1: hp = hgat @ Wpr
  f32x4 acc1[2][4] = {};
#pragma unroll
  for (int ks = 0; ks < 4; ks++) {
    int k2 = ks * 64 + lk * 16;
    bf16x8 af[2], bfr[4];
#pragma unroll
    for (int mt = 0; mt < 2; mt++) {
      int arr = wm * 32 + mt * 16 + lr;
      af[mt] = *(const bf16x8*)(As + arr * 256 + (k2 ^ ((arr & 7) << 4)));
    }
#pragma unroll
    for (int nt = 0; nt < 4; nt++) {
      int bn = wn * 64 + nt * 16 + lr;
      bfr[nt] = *(const bf16x8*)(Tpr + (size_t)bn * 128 + ks * 32 + lk * 8);
    }
#pragma unroll
    for (int mt = 0; mt < 2; mt++)
#pragma unroll
      for (int nt = 0; nt < 4; nt++)
        acc1[mt][nt] = __builtin_amdgcn_mfma_f32_16x16x32_bf16(
            af[mt], bfr[nt], acc1[mt][nt], 0, 0, 0);
  }
#pragma unroll
  for (int mt = 0; mt < 2; mt++) {
#pragma unroll
    for (int r = 0; r < 4; r++) {
      int lrow = wm * 32 + mt * 16 + lk * 4 + r;
#pragma unroll
      for (int nt = 0; nt < 4; nt++) {
        int col = wn * 64 + nt * 16 + lr;
        acc1[mt][nt][r] += bpv[nt];
        *(ushort*)(Hs + lrow * 512 + ((2 * col) ^ ((lrow & 7) << 4))) =
            f2b(acc1[mt][nt][r]);
      }
    }
  }
  __syncthreads();

  // MFMA2: v = [hp|ctx] @ Wgt (K=256)
  f32x4 acc2[2][4] = {};
#pragma unroll
  for (int ks = 0; ks < 8; ks++) {
    int k2 = ks * 64 + lk * 16;
    bf16x8 af[2], bfr[4];
#pragma unroll
    for (int mt = 0; mt < 2; mt++) {
      int arr = wm * 32 + mt * 16 + lr;
      af[mt] = *(const bf16x8*)(Hs + arr * 512 + (k2 ^ ((arr & 7) << 4)));
    }
#pragma unroll
    for (int nt = 0; nt < 4; nt++) {
      int bn = wn * 64 + nt * 16 + lr;
      bfr[nt] = *(const bf16x8*)(Tgt + (size_t)bn * 256 + ks * 32 + lk * 8);
    }
#pragma unroll
    for (int mt = 0; mt < 2; mt++)
#pragma unroll
      for (int nt = 0; nt < 4; nt++)
        acc2[mt][nt] = __builtin_amdgcn_mfma_f32_16x16x32_bf16(
            af[mt], bfr[nt], acc2[mt][nt], 0, 0, 0);
  }

#pragma unroll
  for (int mt = 0; mt < 2; mt++) {
#pragma unroll
    for (int r = 0; r < 4; r++) {
      int lrow = wm * 32 + mt * 16 + lk * 4 + r;
      int row  = row0 + lrow;
      if (row >= M) continue;
#pragma unroll
      for (int nt = 0; nt < 4; nt++) {
        int col = wn * 64 + nt * 16 + lr;
        float hp = acc1[mt][nt][r];
        float cx = b2f(*(const ushort*)(Hs + lrow * 512 +
                        ((2 * col + 256) ^ ((lrow & 7) << 4))));
        float g = 1.f / (1.f + __expf(-(acc2[mt][nt][r] + bgv[nt])));
        out[(size_t)row * 128 + col] = cx + g * (hp - cx);
      }
    }
  }
}

// ---------------------------------------------------------------------------
// Aggregation: one wave per dst node; lane covers features (2l,2l+1) bf16.
// a precomputed (bsort); inner loop = shfl + a-read + feat gather + 2 fma.
// ---------------------------------------------------------------------------
__global__ __launch_bounds__(256) void agg_k(
    const ushort* __restrict__ featb, const uint2* __restrict__ a_srt,
    const int* __restrict__ deg, const int* __restrict__ row_off,
    const int* __restrict__ ssrc, const float* __restrict__ bias,
    ushort* __restrict__ hgatb)
{
  const int wid = (blockIdx.x * 256 + threadIdx.x) >> 6;
  if (wid >= NN) return;
  const int ln = threadIdx.x & 63;
  const int head = ln >> 4;
  const int cnt = deg[wid];
  const int start = row_off[wid];
  const uint* f2 = (const uint*)featb;

  float ax0 = 0.f, ay0 = 0.f, dn0 = 0.f;
  float ax1 = 0.f, ay1 = 0.f, dn1 = 0.f;
  for (int base = 0; base < cnt; base += 64) {
    int m = min(64, cnt - base);
    int sv = (ln < m) ? ssrc[start + base + ln] : 0;
    int i = 0;
    for (; i + 3 < m; i += 4) {
      int s0 = __shfl(sv, i),     s1 = __shfl(sv, i + 1);
      int s2 = __shfl(sv, i + 2), s3 = __shfl(sv, i + 3);
      uint2 w0 = a_srt[start + base + i];
      uint2 w1 = a_srt[start + base + i + 1];
      uint2 w2 = a_srt[start + base + i + 2];
      uint2 w3 = a_srt[start + base + i + 3];
      uint u0 = f2[(size_t)s0 * 64 + ln], u1 = f2[(size_t)s1 * 64 + ln];
      uint u2 = f2[(size_t)s2 * 64 + ln], u3 = f2[(size_t)s3 * 64 + ln];
      uint q0 = (head & 2) ? w0.y : w0.x;
      uint q1 = (head & 2) ? w1.y : w1.x;
      uint q2 = (head & 2) ? w2.y : w2.x;
      uint q3 = (head & 2) ? w3.y : w3.x;
      float a0 = b2f((ushort)((head & 1) ? (q0 >> 16) : (q0 & 0xffff)));
      float a1 = b2f((ushort)((head & 1) ? (q1 >> 16) : (q1 & 0xffff)));
      float a2 = b2f((ushort)((head & 1) ? (q2 >> 16) : (q2 & 0xffff)));
      float a3 = b2f((ushort)((head & 1) ? (q3 >> 16) : (q3 & 0xffff)));
      ax0 = fmaf(a0, b2f((ushort)(u0 & 0xffff)), ax0);
      ay0 = fmaf(a0, b2f((ushort)(u0 >> 16)), ay0);
      ax1 = fmaf(a1, b2f((ushort)(u1 & 0xffff)), ax1);
      ay1 = fmaf(a1, b2f((ushort)(u1 >> 16)), ay1);
      ax0 = fmaf(a2, b2f((ushort)(u2 & 0xffff)), ax0);
      ay0 = fmaf(a2, b2f((ushort)(u2 >> 16)), ay0);
      ax1 = fmaf(a3, b2f((ushort)(u3 & 0xffff)), ax1);
      ay1 = fmaf(a3, b2f((ushort)(u3 >> 16)), ay1);
      dn0 += a0 + a2;
      dn1 += a1 + a3;
    }
    for (; i < m; i++) {
      int s0 = __shfl(sv, i);
      uint2 w0 = a_srt[start + base + i];
      uint u0 = f2[(size_t)s0 * 64 + ln];
      uint q0 = (head & 2) ? w0.y : w0.x;
      float a0 = b2f((ushort)((head & 1) ? (q0 >> 16) : (q0 & 0xffff)));
      ax0 = fmaf(a0, b2f((ushort)(u0 & 0xffff)), ax0);
      ay0 = fmaf(a0, b2f((ushort)(u0 >> 16)), ay0);
      dn0 += a0;
    }
  }
  float dn = dn0 + dn1;
  float inv = (cnt > 0) ? (1.0f / dn) : 0.0f;
  float2 bv = ((const float2*)bias)[ln];
  float rx = fmaf(ax0 + ax1, inv, bv.x);
  float ry = fmaf(ay0 + ay1, inv, bv.y);
  rx = rx > 0.f ? rx : expm1f(rx);
  ry = ry > 0.f ? ry : expm1f(ry);
  uint o = (uint)f2b(rx) | ((uint)f2b(ry) << 16);
  ((uint*)hgatb)[(size_t)wid * 64 + ln] = o;
}

// ---------------------------------------------------------------------------
extern "C" void kernel_launch(void* const* d_in, const int* in_sizes, int n_in,
                              void* d_out, int out_size, void* d_ws, size_t ws_size,
                              hipStream_t stream) {
  const float* h        = (const float*)d_in[0];
  const int*   src      = (const int*)d_in[1];
  const int*   dst      = (const int*)d_in[2];
  const float* ctx      = (const float*)d_in[3];
  const float* W_fc     = (const float*)d_in[4];
  const float* attn_l   = (const float*)d_in[5];
  const float* attn_r   = (const float*)d_in[6];
  const float* bias_gat = (const float*)d_in[7];
  const float* W_proj   = (const float*)d_in[8];
  const float* b_proj   = (const float*)d_in[9];
  const float* W_gate   = (const float*)d_in[10];
  const float* b_gate   = (const float*)d_in[11];
  float* out = (float*)d_out;

  char* ws = (char*)d_ws;
  size_t off = 0;
  auto take = [&](size_t bytes) -> void* {
    void* p = ws + off;
    off += (bytes + 255) & ~(size_t)255;
    return p;
  };
  ushort* featb  = (ushort*)take((size_t)NN * 128 * 2);
  ushort* hgatb  = (ushort*)take((size_t)NN * 128 * 2);
  float*  el     = (float*)take((size_t)NN * 4 * 4);
  float*  er     = (float*)take((size_t)NN * 4 * 4);
  int*    gcnt   = (int*)take((size_t)NBK * CSTR * 4);
  int*    boff   = (int*)take((size_t)(NBK + 1) * 4);
  int*    gcur   = (int*)take((size_t)NBK * CSTR * 4);
  uint*   packed = (uint*)take((size_t)NE * 4);
  int*    ssrc   = (int*)take((size_t)NE * 4);
  uint2*  a_srt  = (uint2*)take((size_t)NE * 8);
  int*    row_off= (int*)take((size_t)NN * 4);
  int*    deg    = (int*)take((size_t)NN * 4);
  ushort* Tfc    = (ushort*)take(16384 * 2);
  ushort* Tpr    = (ushort*)take(16384 * 2);
  ushort* Tgt    = (ushort*)take(32768 * 2);

  hipMemsetAsync(gcnt, 0, (size_t)NBK * CSTR * 4, stream);

  const int gb = (NN + 63) / 64;         // 782
  const size_t smem4 = 64 * 256;         // 16 KB (A-tile only)

  cvt_w<<<256, 256, 0, stream>>>(W_fc, W_proj, W_gate, Tfc, Tpr, Tgt);
  // feat = h @ W_fc (f32 in, bf16 out) + fused el/er (needed by bsort)
  mgemm0<<<gb, 256, smem4, stream>>>(h, Tfc, attn_l, attn_r, el, er, featb, NN);
  // bucket partition + fused sort/attention-coefficients -> CSR + a_srt
  bhist<<<64, 1024, 0, stream>>>(dst, gcnt);
  bscan<<<1, 256, 0, stream>>>(gcnt, boff, gcur);
  bscatter<<<64, 1024, 0, stream>>>(src, dst, gcur, packed);
  bsort<<<NBK, 256, 0, stream>>>(packed, boff, el, er, ssrc, a_srt,
                                 row_off, deg);
  // edge-softmax aggregation -> h_gat (bf16)
  agg_k<<<12500, 256, 0, stream>>>(featb, a_srt, deg, row_off, ssrc,
                                   bias_gat, hgatb);
  // fused: hp = hgat@Wpr + b; out = blend(sigmoid([hp|ctx]@Wgt + bg), hp, ctx)
  pg_k<<<gb, 256, 0, stream>>>(hgatb, ctx, Tpr, Tgt, b_proj, b_gate, out, NN);
}